// Round 7
// baseline (233.200 us; speedup 1.0000x reference)
//
#include <hip/hip_runtime.h>
#include <hip/hip_bf16.h>
#include <math.h>

#define NQ 8192   // queries
#define MK 8192   // keys
#define CD 512    // embed dim
#define LN 64     // neighbors per query
#define HH 8      // heads
#define HD 64     // head dim
#define BB 16     // batches

typedef short short8 __attribute__((ext_vector_type(8)));
typedef float floatx4 __attribute__((ext_vector_type(4)));

// fp32 -> bf16 RNE scalar
__device__ __forceinline__ unsigned short f2bf(float x) {
    unsigned int u = __builtin_bit_cast(unsigned int, x);
    return (unsigned short)((u + 0x7FFFu + ((u >> 16) & 1u)) >> 16);
}
// packed pair via HW v_cvt_pk_bf16_f32 on gfx950
__device__ __forceinline__ unsigned int pkbf(float lo, float hi) {
    float2 f; f.x = lo; f.y = hi;
    __hip_bfloat162 h2 = __float22bfloat162_rn(f);
    unsigned int u;
    __builtin_memcpy(&u, &h2, 4);
    return u;
}
// bf16 pair low element -> float (exact)
__device__ __forceinline__ float bflo(unsigned int u) {
    return __builtin_bit_cast(float, u << 16);
}
// bf16 pair high element -> float WITH low-half junk bits: value is
// hi*(1+d), |d| <= 2^-8 (junk sits below bf16's own mantissa) — cheaper
// than masking (0 VALU) and within bf16 rounding noise for this problem.
__device__ __forceinline__ float bfhij(unsigned int u) {
    return __builtin_bit_cast(float, u);
}
__device__ __forceinline__ short8 u4s8(uint4 u) {
    short8 s; __builtin_memcpy(&s, &u, 16); return s;
}

// async global->LDS, 16B per lane; LDS dest = wave-uniform base + lane*16
__device__ __forceinline__ void gl_lds16(const unsigned short* g, unsigned short* l) {
    __builtin_amdgcn_global_load_lds(
        (const __attribute__((address_space(1))) unsigned int*)g,
        (__attribute__((address_space(3))) unsigned int*)l, 16, 0, 0);
}

// ---------------------------------------------------------------------------
// fp32 -> bf16 conversion prepass (5 segments in one launch)
// ---------------------------------------------------------------------------
struct ConvSeg { const float* src; unsigned short* dst; int n4; };
struct ConvArgs { ConvSeg s[5]; };

__global__ __launch_bounds__(256) void convert_bf16(ConvArgs a) {
    const int seg = blockIdx.y;
    const int i = blockIdx.x * 256 + threadIdx.x;
    if (i >= a.s[seg].n4) return;
    const float4 v = ((const float4*)a.s[seg].src)[i];
    uint2 o; o.x = pkbf(v.x, v.y); o.y = pkbf(v.z, v.w);
    ((uint2*)a.s[seg].dst)[i] = o;
}

// ---------------------------------------------------------------------------
// m97-style bf16 NT GEMM (see R6 comments). Epilogue: bf16 out (qkv path,
// scale folded before rounding) or fp32 out (final projection).
// ---------------------------------------------------------------------------
__device__ __forceinline__ void gemm_bf_body(const unsigned short* __restrict__ A,
                                             const unsigned short* __restrict__ W,
                                             const float* __restrict__ bias,
                                             float* __restrict__ outf,
                                             unsigned short* __restrict__ outb,
                                             float scale) {
    __shared__ unsigned short As[128 * 64];
    __shared__ unsigned short Bs[128 * 64];

    const int tid  = threadIdx.x;
    const int row0 = blockIdx.x * 128;
    const int col0 = blockIdx.y * 128;

    const int w    = tid >> 6;
    const int lane = tid & 63;
    const int wr   = w >> 1;
    const int wc   = w & 1;
    const int q    = lane >> 4;    // quad
    const int ml   = lane & 15;

    const int sr = lane >> 3;            // 0..7 (== row&7 of the loaded row)
    const int sg = (lane & 7) ^ sr;      // XOR-swizzled source granule
    const unsigned short* Ap = A + (size_t)(row0 + w * 32 + sr) * CD + sg * 8;
    const unsigned short* Wp = W + (size_t)(col0 + w * 32 + sr) * CD + sg * 8;
    unsigned short* Asw = &As[(w * 32) * 64];
    unsigned short* Bsw = &Bs[(w * 32) * 64];

    floatx4 acc[4][4];
#pragma unroll
    for (int i = 0; i < 4; ++i)
#pragma unroll
        for (int j = 0; j < 4; ++j)
            acc[i][j] = (floatx4){0.f, 0.f, 0.f, 0.f};

    for (int k0 = 0; k0 < CD; k0 += 64) {
        __syncthreads();
#pragma unroll
        for (int i = 0; i < 4; ++i) {
            gl_lds16(Ap + (size_t)(i * 8) * CD + k0, Asw + i * 8 * 64);
            gl_lds16(Wp + (size_t)(i * 8) * CD + k0, Bsw + i * 8 * 64);
        }
        __syncthreads();

#pragma unroll
        for (int kw = 0; kw < 2; ++kw) {
            short8 af[4], bf[4];
            const int gp = ((kw * 4 + q) ^ (ml & 7)) * 8;
#pragma unroll
            for (int mi = 0; mi < 4; ++mi)
                af[mi] = *(const short8*)&As[(wr * 64 + mi * 16 + ml) * 64 + gp];
#pragma unroll
            for (int ni = 0; ni < 4; ++ni)
                bf[ni] = *(const short8*)&Bs[(wc * 64 + ni * 16 + ml) * 64 + gp];
#pragma unroll
            for (int mi = 0; mi < 4; ++mi)
#pragma unroll
                for (int ni = 0; ni < 4; ++ni)
                    acc[mi][ni] = __builtin_amdgcn_mfma_f32_16x16x32_bf16(
                        af[mi], bf[ni], acc[mi][ni], 0, 0, 0);
        }
    }

    float bv[4];
#pragma unroll
    for (int ni = 0; ni < 4; ++ni)
        bv[ni] = bias[col0 + wc * 64 + ni * 16 + ml];
#pragma unroll
    for (int mi = 0; mi < 4; ++mi) {
#pragma unroll
        for (int ni = 0; ni < 4; ++ni) {
            const int cg = col0 + wc * 64 + ni * 16 + ml;
#pragma unroll
            for (int r = 0; r < 4; ++r) {
                const int rg = row0 + wr * 64 + mi * 16 + q * 4 + r;
                const float val = (acc[mi][ni][r] + bv[ni]) * scale;
                if (outb) outb[(size_t)rg * CD + cg] = f2bf(val);
                else      outf[(size_t)rg * CD + cg] = val;
            }
        }
    }
}

// qkv: z=0 -> q bf16 (scale 0.125 folded pre-round); z=1 -> k bf16; z=2 -> v bf16
__global__ __launch_bounds__(256) void qkv_gemm(const unsigned short* __restrict__ A_bf,
                                                const unsigned short* __restrict__ w_bf,
                                                const float* __restrict__ bias,
                                                unsigned short* __restrict__ q_bf,
                                                unsigned short* __restrict__ k_bf,
                                                unsigned short* __restrict__ v_bf) {
    const int z = blockIdx.z;
    const unsigned short* A = A_bf + (size_t)z * NQ * CD;
    unsigned short* outb = (z == 0) ? q_bf : ((z == 1) ? k_bf : v_bf);
    gemm_bf_body(A, w_bf + (size_t)z * CD * CD, bias + (size_t)z * CD,
                 nullptr, outb, (z == 0) ? 0.125f : 1.0f);
}

__global__ __launch_bounds__(256) void out_gemm(const unsigned short* __restrict__ A,
                                                const unsigned short* __restrict__ W,
                                                const float* __restrict__ bias,
                                                float* __restrict__ out) {
    gemm_bf_body(A, W, bias, out, nullptr, 1.0f);
}

// ---------------------------------------------------------------------------
// Attention: 1 block per query, 8 waves = 8 heads.
// Score phase on MFMA: per 16-neighbor group, A-frag = gathered K rows
//   (lane ml -> row gs[g*16+ml], quad -> 16B dim chunk; layout
//   A[m=lane&15][k=quad*8+j] — verified by the GEMM above), B-frag = q
//   broadcast to all 16 cols; 2 chained 16x16x32 MFMAs cover K=64.
//   D col=lane&15,row=quad*4+reg -> ml==0 lanes publish scores to LDS.
// Softmax: lane = neighbor (unchanged). PV: VALU fma with junk-hi unpack.
// ---------------------------------------------------------------------------
__global__ __launch_bounds__(512) void attn_kernel(
    const unsigned short* __restrict__ q_bf,     // NQ*CD bf16 (pre-scaled)
    const unsigned short* __restrict__ k_bf,     // NQ*CD bf16
    const unsigned short* __restrict__ v_bf,     // NQ*CD bf16
    const int* __restrict__ index_pair,          // (NQ, LN)
    const int* __restrict__ key_batch_cnt,       // (BB,)
    const int* __restrict__ index_pair_batch,    // (NQ,)
    unsigned short* __restrict__ attn_bf,        // NQ*CD bf16
    float* __restrict__ out2) {                  // NQ*LN
    const int j = blockIdx.x;
    const int n = (j & 7) * (NQ / 8) + (j >> 3);   // XCD-L2 locality swizzle

    const int tid  = threadIdx.x;
    const int h    = tid >> 6;     // wave id = head
    const int lane = tid & 63;
    const int quad = lane >> 4;    // 0..3
    const int ml   = lane & 15;

    __shared__ float wmat[HH][LN];
    __shared__ int   gs[LN];

    if (tid < LN) {
        const int batch = index_pair_batch[n];
        int offset = 0;
        for (int b = 0; b < batch; ++b) offset += key_batch_cnt[b];
        const int gi = index_pair[n * LN + tid];
        gs[tid] = (gi >= 0) ? (gi + offset) : 0;   // reference safe-gather
    }
    __syncthreads();

    // --- scores via MFMA ---------------------------------------------------
    // B-frags: q dims quad*8.. and 32+quad*8.. (broadcast across ml)
    const char* qp = (const char*)q_bf + (size_t)n * (CD * 2) + h * (HD * 2) + quad * 16;
    const short8 bq0 = u4s8(*(const uint4*)qp);
    const short8 bq1 = u4s8(*(const uint4*)(qp + 64));

    int gr[4];
#pragma unroll
    for (int g = 0; g < 4; ++g) gr[g] = gs[g * 16 + ml];
    uint4 a0[4], a1[4];
#pragma unroll
    for (int g = 0; g < 4; ++g) {
        const char* kp = (const char*)k_bf + (size_t)gr[g] * (CD * 2) + h * (HD * 2) + quad * 16;
        a0[g] = *(const uint4*)kp;
        a1[g] = *(const uint4*)(kp + 64);
    }
#pragma unroll
    for (int g = 0; g < 4; ++g) {
        floatx4 sa = (floatx4){0.f, 0.f, 0.f, 0.f};
        sa = __builtin_amdgcn_mfma_f32_16x16x32_bf16(u4s8(a0[g]), bq0, sa, 0, 0, 0);
        sa = __builtin_amdgcn_mfma_f32_16x16x32_bf16(u4s8(a1[g]), bq1, sa, 0, 0, 0);
        if (ml == 0) {   // col 0 lanes publish: neighbor l = g*16 + quad*4 + r
#pragma unroll
            for (int r = 0; r < 4; ++r) wmat[h][g * 16 + quad * 4 + r] = sa[r];
        }
    }

    // --- softmax over 64 lanes (lane = neighbor; same-wave LDS RAW ok) ----
    float score = wmat[h][lane];
    if (index_pair[n * LN + lane] < 0) score = -1000.0f;   // MASK_VAL
    float mx = score;
#pragma unroll
    for (int o = 32; o > 0; o >>= 1) mx = fmaxf(mx, __shfl_xor(mx, o, 64));
    float e = __expf(score - mx);           // masked lanes underflow to 0
    float s = e;
#pragma unroll
    for (int o = 32; o > 0; o >>= 1) s += __shfl_xor(s, o, 64);
    const float w = e / s;
    wmat[h][lane] = w;
    __syncthreads();   // publish w for out2 (cross-wave read below)

    // --- PV: lane (r,dg) = (neighbor-in-group, dim-group of 8) ------------
    const int r  = lane >> 3;
    const int dg = lane & 7;
    unsigned int off[8];
#pragma unroll
    for (int it = 0; it < 8; ++it)
        off[it] = (unsigned int)gs[it * 8 + r] * (CD * 2) + h * (HD * 2) + dg * 16;

    float a8[8] = {0.f, 0.f, 0.f, 0.f, 0.f, 0.f, 0.f, 0.f};
#pragma unroll
    for (int it = 0; it < 8; ++it) {
        const float wl = __shfl(w, it * 8 + r, 64);
        const uint4 vv = *(const uint4*)((const char*)v_bf + off[it]);
        a8[0] = fmaf(wl, bflo(vv.x),  a8[0]);
        a8[1] = fmaf(wl, bfhij(vv.x), a8[1]);
        a8[2] = fmaf(wl, bflo(vv.y),  a8[2]);
        a8[3] = fmaf(wl, bfhij(vv.y), a8[3]);
        a8[4] = fmaf(wl, bflo(vv.z),  a8[4]);
        a8[5] = fmaf(wl, bfhij(vv.z), a8[5]);
        a8[6] = fmaf(wl, bflo(vv.w),  a8[6]);
        a8[7] = fmaf(wl, bfhij(vv.w), a8[7]);
    }
#pragma unroll
    for (int o = 8; o <= 32; o <<= 1)
#pragma unroll
        for (int d = 0; d < 8; ++d) a8[d] += __shfl_xor(a8[d], o, 64);
    // lane (r,dg) stores dim dg*8+r (permuted within the 256B segment)
    attn_bf[(size_t)n * CD + h * HD + dg * 8 + r] = f2bf(a8[r]);

    // --- output 2: sum over heads / H -------------------------------------
    if (tid < LN) {
        float s8 = 0.f;
#pragma unroll
        for (int hh = 0; hh < HH; ++hh) s8 += wmat[hh][tid];
        out2[(size_t)n * LN + tid] = s8 * (1.0f / HH);
    }
}

// ---------------------------------------------------------------------------
extern "C" void kernel_launch(void* const* d_in, const int* in_sizes, int n_in,
                              void* d_out, int out_size, void* d_ws, size_t ws_size,
                              hipStream_t stream) {
    const float* query   = (const float*)d_in[0];
    const float* key     = (const float*)d_in[1];
    const float* value   = (const float*)d_in[2];
    const float* ipw     = (const float*)d_in[3];   // (3C, C)
    const float* ipb     = (const float*)d_in[4];   // (3C,)
    const float* out_w   = (const float*)d_in[5];   // (C, C)
    const float* out_b   = (const float*)d_in[6];   // (C,)
    const int*   index_pair       = (const int*)d_in[7];
    // d_in[8] = query_batch_cnt (unused: implied by index_pair_batch)
    const int*   key_batch_cnt    = (const int*)d_in[9];
    const int*   index_pair_batch = (const int*)d_in[10];

    float* out = (float*)d_out;                // [attn (NQ*CD) | out2 (NQ*LN)]
    // ws layout (bf16 unless noted): q 8MB | k 8 | v 8 | A_in 24 | ipw 3 | out_w 1
    unsigned short* q_bf  = (unsigned short*)d_ws;
    unsigned short* k_bf  = q_bf + (size_t)NQ * CD;
    unsigned short* v_bf  = k_bf + (size_t)NQ * CD;
    unsigned short* A_bf  = v_bf + (size_t)NQ * CD;        // 3 * NQ*CD
    unsigned short* w_bf  = A_bf + (size_t)3 * NQ * CD;    // 3 * CD*CD (ipw)
    unsigned short* ow_bf = w_bf + (size_t)3 * CD * CD;    // CD*CD (out_w)
    // attn output (bf16) reuses the A_bf query slot (qkv_gemm done with it)
    unsigned short* attn_bf = A_bf;

    // 0) convert inputs/weights to bf16
    ConvArgs ca;
    ca.s[0] = {query, A_bf,                       NQ * CD / 4};
    ca.s[1] = {key,   A_bf + (size_t)NQ * CD,     NQ * CD / 4};
    ca.s[2] = {value, A_bf + (size_t)2 * NQ * CD, NQ * CD / 4};
    ca.s[3] = {ipw,   w_bf,                       3 * CD * CD / 4};
    ca.s[4] = {out_w, ow_bf,                      CD * CD / 4};
    dim3 g0(NQ * CD / 4 / 256, 5);
    convert_bf16<<<g0, 256, 0, stream>>>(ca);

    // 1) q/k/v projections (all bf16 out; q pre-scaled by 0.125)
    dim3 g1(NQ / 128, CD / 128, 3);
    qkv_gemm<<<g1, 256, 0, stream>>>(A_bf, w_bf, ipb, q_bf, k_bf, v_bf);

    // 2) gather attention -> bf16 attn + output 2
    attn_kernel<<<NQ, 512, 0, stream>>>(q_bf, k_bf, v_bf, index_pair,
                                        key_batch_cnt, index_pair_batch,
                                        attn_bf, out + (size_t)NQ * CD);

    // 3) out projection -> output 1
    dim3 g3(NQ / 128, CD / 128, 1);
    out_gemm<<<g3, 256, 0, stream>>>(attn_bf, ow_bf, out_b, out);
}

// Round 8
// 223.707 us; speedup vs baseline: 1.0424x; 1.0424x over previous
//
#include <hip/hip_runtime.h>
#include <hip/hip_bf16.h>
#include <math.h>

#define NQ 8192   // queries
#define MK 8192   // keys
#define CD 512    // embed dim
#define LN 64     // neighbors per query
#define HH 8      // heads
#define HD 64     // head dim
#define BB 16     // batches

typedef short short8 __attribute__((ext_vector_type(8)));
typedef float floatx4 __attribute__((ext_vector_type(4)));

// fp32 -> bf16 RNE scalar
__device__ __forceinline__ unsigned short f2bf(float x) {
    unsigned int u = __builtin_bit_cast(unsigned int, x);
    return (unsigned short)((u + 0x7FFFu + ((u >> 16) & 1u)) >> 16);
}
// packed pair via HW v_cvt_pk_bf16_f32 on gfx950
__device__ __forceinline__ unsigned int pkbf(float lo, float hi) {
    float2 f; f.x = lo; f.y = hi;
    __hip_bfloat162 h2 = __float22bfloat162_rn(f);
    unsigned int u;
    __builtin_memcpy(&u, &h2, 4);
    return u;
}
// bf16 pair low element -> float (exact)
__device__ __forceinline__ float bflo(unsigned int u) {
    return __builtin_bit_cast(float, u << 16);
}
// bf16 pair high element -> float WITH low-half junk bits: hi*(1+d),
// |d| <= 2^-8 — below bf16's own rounding noise; saves the mask op.
__device__ __forceinline__ float bfhij(unsigned int u) {
    return __builtin_bit_cast(float, u);
}
__device__ __forceinline__ short8 u4s8(uint4 u) {
    short8 s; __builtin_memcpy(&s, &u, 16); return s;
}

// async global->LDS, 16B per lane; LDS dest = wave-uniform base + lane*16
__device__ __forceinline__ void gl_lds16(const unsigned short* g, unsigned short* l) {
    __builtin_amdgcn_global_load_lds(
        (const __attribute__((address_space(1))) unsigned int*)g,
        (__attribute__((address_space(3))) unsigned int*)l, 16, 0, 0);
}

// ---------------------------------------------------------------------------
// fp32 -> bf16 conversion prepass (5 segments in one launch)
// ---------------------------------------------------------------------------
struct ConvSeg { const float* src; unsigned short* dst; int n4; };
struct ConvArgs { ConvSeg s[5]; };

__global__ __launch_bounds__(256) void convert_bf16(ConvArgs a) {
    const int seg = blockIdx.y;
    const int i = blockIdx.x * 256 + threadIdx.x;
    if (i >= a.s[seg].n4) return;
    const float4 v = ((const float4*)a.s[seg].src)[i];
    uint2 o; o.x = pkbf(v.x, v.y); o.y = pkbf(v.z, v.w);
    ((uint2*)a.s[seg].dst)[i] = o;
}

// ---------------------------------------------------------------------------
// m97-style bf16 NT GEMM (see R6 comments). Epilogue: bf16 out (qkv path,
// scale folded before rounding) or fp32 out (final projection).
// ---------------------------------------------------------------------------
__device__ __forceinline__ void gemm_bf_body(const unsigned short* __restrict__ A,
                                             const unsigned short* __restrict__ W,
                                             const float* __restrict__ bias,
                                             float* __restrict__ outf,
                                             unsigned short* __restrict__ outb,
                                             float scale) {
    __shared__ unsigned short As[128 * 64];
    __shared__ unsigned short Bs[128 * 64];

    const int tid  = threadIdx.x;
    const int row0 = blockIdx.x * 128;
    const int col0 = blockIdx.y * 128;

    const int w    = tid >> 6;
    const int lane = tid & 63;
    const int wr   = w >> 1;
    const int wc   = w & 1;
    const int q    = lane >> 4;    // quad
    const int ml   = lane & 15;

    const int sr = lane >> 3;            // 0..7 (== row&7 of the loaded row)
    const int sg = (lane & 7) ^ sr;      // XOR-swizzled source granule
    const unsigned short* Ap = A + (size_t)(row0 + w * 32 + sr) * CD + sg * 8;
    const unsigned short* Wp = W + (size_t)(col0 + w * 32 + sr) * CD + sg * 8;
    unsigned short* Asw = &As[(w * 32) * 64];
    unsigned short* Bsw = &Bs[(w * 32) * 64];

    floatx4 acc[4][4];
#pragma unroll
    for (int i = 0; i < 4; ++i)
#pragma unroll
        for (int j = 0; j < 4; ++j)
            acc[i][j] = (floatx4){0.f, 0.f, 0.f, 0.f};

    for (int k0 = 0; k0 < CD; k0 += 64) {
        __syncthreads();
#pragma unroll
        for (int i = 0; i < 4; ++i) {
            gl_lds16(Ap + (size_t)(i * 8) * CD + k0, Asw + i * 8 * 64);
            gl_lds16(Wp + (size_t)(i * 8) * CD + k0, Bsw + i * 8 * 64);
        }
        __syncthreads();

#pragma unroll
        for (int kw = 0; kw < 2; ++kw) {
            short8 af[4], bf[4];
            const int gp = ((kw * 4 + q) ^ (ml & 7)) * 8;
#pragma unroll
            for (int mi = 0; mi < 4; ++mi)
                af[mi] = *(const short8*)&As[(wr * 64 + mi * 16 + ml) * 64 + gp];
#pragma unroll
            for (int ni = 0; ni < 4; ++ni)
                bf[ni] = *(const short8*)&Bs[(wc * 64 + ni * 16 + ml) * 64 + gp];
#pragma unroll
            for (int mi = 0; mi < 4; ++mi)
#pragma unroll
                for (int ni = 0; ni < 4; ++ni)
                    acc[mi][ni] = __builtin_amdgcn_mfma_f32_16x16x32_bf16(
                        af[mi], bf[ni], acc[mi][ni], 0, 0, 0);
        }
    }

    float bv[4];
#pragma unroll
    for (int ni = 0; ni < 4; ++ni)
        bv[ni] = bias[col0 + wc * 64 + ni * 16 + ml];
#pragma unroll
    for (int mi = 0; mi < 4; ++mi) {
#pragma unroll
        for (int ni = 0; ni < 4; ++ni) {
            const int cg = col0 + wc * 64 + ni * 16 + ml;
#pragma unroll
            for (int r = 0; r < 4; ++r) {
                const int rg = row0 + wr * 64 + mi * 16 + q * 4 + r;
                const float val = (acc[mi][ni][r] + bv[ni]) * scale;
                if (outb) outb[(size_t)rg * CD + cg] = f2bf(val);
                else      outf[(size_t)rg * CD + cg] = val;
            }
        }
    }
}

// qkv: z=0 -> q bf16 (scale 0.125 folded pre-round); z=1 -> k bf16; z=2 -> v bf16
__global__ __launch_bounds__(256) void qkv_gemm(const unsigned short* __restrict__ A_bf,
                                                const unsigned short* __restrict__ w_bf,
                                                const float* __restrict__ bias,
                                                unsigned short* __restrict__ q_bf,
                                                unsigned short* __restrict__ k_bf,
                                                unsigned short* __restrict__ v_bf) {
    const int z = blockIdx.z;
    const unsigned short* A = A_bf + (size_t)z * NQ * CD;
    unsigned short* outb = (z == 0) ? q_bf : ((z == 1) ? k_bf : v_bf);
    gemm_bf_body(A, w_bf + (size_t)z * CD * CD, bias + (size_t)z * CD,
                 nullptr, outb, (z == 0) ? 0.125f : 1.0f);
}

__global__ __launch_bounds__(256) void out_gemm(const unsigned short* __restrict__ A,
                                                const unsigned short* __restrict__ W,
                                                const float* __restrict__ bias,
                                                float* __restrict__ out) {
    gemm_bf_body(A, W, bias, out, nullptr, 1.0f);
}

// ---------------------------------------------------------------------------
// Attention: 1 block per query, 8 waves = 8 heads.
// Latency-restructured (R8): parallel prefix for key offsets (no serial
// load chain), ALL k+v gathers issued before softmax (v doesn't depend on
// w), single end-of-kernel barrier. Scores on MFMA (layout proven by the
// GEMM above); PV on VALU fma with junk-hi unpack.
// ---------------------------------------------------------------------------
__global__ __launch_bounds__(512, 4) void attn_kernel(
    const unsigned short* __restrict__ q_bf,     // NQ*CD bf16 (pre-scaled)
    const unsigned short* __restrict__ k_bf,     // NQ*CD bf16
    const unsigned short* __restrict__ v_bf,     // NQ*CD bf16
    const int* __restrict__ index_pair,          // (NQ, LN)
    const int* __restrict__ key_batch_cnt,       // (BB,)
    const int* __restrict__ index_pair_batch,    // (NQ,)
    unsigned short* __restrict__ attn_bf,        // NQ*CD bf16
    float* __restrict__ out2) {                  // NQ*LN
    const int j = blockIdx.x;
    const int n = (j & 7) * (NQ / 8) + (j >> 3);   // XCD-L2 locality swizzle

    const int tid  = threadIdx.x;
    const int h    = tid >> 6;     // wave id = head
    const int lane = tid & 63;
    const int quad = lane >> 4;    // 0..3
    const int ml   = lane & 15;

    __shared__ float wmat[HH][LN];
    __shared__ int   gs[LN];
    __shared__ unsigned long long smask;

    if (tid < LN) {
        // parallel prefix-sum of key_batch_cnt (replaces serial load loop)
        int incl = (lane < BB) ? key_batch_cnt[lane] : 0;
#pragma unroll
        for (int d = 1; d < BB; d <<= 1) {
            const int t = __shfl_up(incl, d, 64);
            if (lane >= d) incl += t;
        }
        const int batch = index_pair_batch[n];
        int off0 = 0;
        if (batch > 0) off0 = __shfl(incl, batch - 1, 64);
        const int gi = index_pair[n * LN + lane];
        const unsigned long long vm = __ballot(gi >= 0);
        if (lane == 0) smask = vm;
        gs[lane] = (gi >= 0) ? (gi + off0) : 0;   // reference safe-gather
    }
    __syncthreads();

    // --- issue ALL gathers up front ---------------------------------------
    // score A-frag (k rows): lane ml -> row gs[g*16+ml], quad -> 16B chunk
    const char* qp = (const char*)q_bf + (size_t)n * (CD * 2) + h * (HD * 2) + quad * 16;
    const short8 bq0 = u4s8(*(const uint4*)qp);
    const short8 bq1 = u4s8(*(const uint4*)(qp + 64));

    int gr[4];
#pragma unroll
    for (int g = 0; g < 4; ++g) gr[g] = gs[g * 16 + ml];
    uint4 a0[4], a1[4];
#pragma unroll
    for (int g = 0; g < 4; ++g) {
        const char* kp = (const char*)k_bf + (size_t)gr[g] * (CD * 2) + h * (HD * 2) + quad * 16;
        a0[g] = *(const uint4*)kp;
        a1[g] = *(const uint4*)(kp + 64);
    }
    // PV v-gathers (depend only on gs, NOT on softmax) — prefetch now
    const int r  = lane >> 3;
    const int dg = lane & 7;
    uint4 vv[8];
#pragma unroll
    for (int it = 0; it < 8; ++it) {
        const unsigned int off = (unsigned int)gs[it * 8 + r] * (CD * 2)
                                 + h * (HD * 2) + dg * 16;
        vv[it] = *(const uint4*)((const char*)v_bf + off);
    }

    // --- scores via MFMA (D col=lane&15, row=quad*4+reg) ------------------
#pragma unroll
    for (int g = 0; g < 4; ++g) {
        floatx4 sa = (floatx4){0.f, 0.f, 0.f, 0.f};
        sa = __builtin_amdgcn_mfma_f32_16x16x32_bf16(u4s8(a0[g]), bq0, sa, 0, 0, 0);
        sa = __builtin_amdgcn_mfma_f32_16x16x32_bf16(u4s8(a1[g]), bq1, sa, 0, 0, 0);
        if (ml == 0) {   // col 0 lanes publish: neighbor l = g*16 + quad*4 + rr
#pragma unroll
            for (int rr = 0; rr < 4; ++rr) wmat[h][g * 16 + quad * 4 + rr] = sa[rr];
        }
    }

    // --- softmax over 64 lanes (lane = neighbor; same-wave LDS RAW ok) ----
    float score = wmat[h][lane];
    if (!((smask >> lane) & 1ull)) score = -1000.0f;   // MASK_VAL
    float mx = score;
#pragma unroll
    for (int o = 32; o > 0; o >>= 1) mx = fmaxf(mx, __shfl_xor(mx, o, 64));
    float e = __expf(score - mx);           // masked lanes underflow to 0
    float s = e;
#pragma unroll
    for (int o = 32; o > 0; o >>= 1) s += __shfl_xor(s, o, 64);
    const float w = e / s;
    wmat[h][lane] = w;    // published for out2 (barrier below, after PV)

    // --- PV: lane (r,dg); v already in registers --------------------------
    float a8[8] = {0.f, 0.f, 0.f, 0.f, 0.f, 0.f, 0.f, 0.f};
#pragma unroll
    for (int it = 0; it < 8; ++it) {
        const float wl = __shfl(w, it * 8 + r, 64);
        a8[0] = fmaf(wl, bflo(vv[it].x),  a8[0]);
        a8[1] = fmaf(wl, bfhij(vv[it].x), a8[1]);
        a8[2] = fmaf(wl, bflo(vv[it].y),  a8[2]);
        a8[3] = fmaf(wl, bfhij(vv[it].y), a8[3]);
        a8[4] = fmaf(wl, bflo(vv[it].z),  a8[4]);
        a8[5] = fmaf(wl, bfhij(vv[it].z), a8[5]);
        a8[6] = fmaf(wl, bflo(vv[it].w),  a8[6]);
        a8[7] = fmaf(wl, bfhij(vv[it].w), a8[7]);
    }
#pragma unroll
    for (int o = 8; o <= 32; o <<= 1)
#pragma unroll
        for (int d = 0; d < 8; ++d) a8[d] += __shfl_xor(a8[d], o, 64);
    // lane (r,dg) stores dim dg*8+r (permuted within the 256B segment)
    attn_bf[(size_t)n * CD + h * HD + dg * 8 + r] = f2bf(a8[r]);

    __syncthreads();   // wmat[*] complete -> out2
    // --- output 2: sum over heads / H -------------------------------------
    if (tid < LN) {
        float s8 = 0.f;
#pragma unroll
        for (int hh = 0; hh < HH; ++hh) s8 += wmat[hh][tid];
        out2[(size_t)n * LN + tid] = s8 * (1.0f / HH);
    }
}

// ---------------------------------------------------------------------------
extern "C" void kernel_launch(void* const* d_in, const int* in_sizes, int n_in,
                              void* d_out, int out_size, void* d_ws, size_t ws_size,
                              hipStream_t stream) {
    const float* query   = (const float*)d_in[0];
    const float* key     = (const float*)d_in[1];
    const float* value   = (const float*)d_in[2];
    const float* ipw     = (const float*)d_in[3];   // (3C, C)
    const float* ipb     = (const float*)d_in[4];   // (3C,)
    const float* out_w   = (const float*)d_in[5];   // (C, C)
    const float* out_b   = (const float*)d_in[6];   // (C,)
    const int*   index_pair       = (const int*)d_in[7];
    // d_in[8] = query_batch_cnt (unused: implied by index_pair_batch)
    const int*   key_batch_cnt    = (const int*)d_in[9];
    const int*   index_pair_batch = (const int*)d_in[10];

    float* out = (float*)d_out;                // [attn (NQ*CD) | out2 (NQ*LN)]
    // ws layout (bf16): q 8MB | k 8 | v 8 | A_in 24 | ipw 3 | out_w 1
    unsigned short* q_bf  = (unsigned short*)d_ws;
    unsigned short* k_bf  = q_bf + (size_t)NQ * CD;
    unsigned short* v_bf  = k_bf + (size_t)NQ * CD;
    unsigned short* A_bf  = v_bf + (size_t)NQ * CD;        // 3 * NQ*CD
    unsigned short* w_bf  = A_bf + (size_t)3 * NQ * CD;    // 3 * CD*CD (ipw)
    unsigned short* ow_bf = w_bf + (size_t)3 * CD * CD;    // CD*CD (out_w)
    // attn output (bf16) reuses the A_bf query slot (qkv_gemm done with it)
    unsigned short* attn_bf = A_bf;

    // 0) convert inputs/weights to bf16
    ConvArgs ca;
    ca.s[0] = {query, A_bf,                       NQ * CD / 4};
    ca.s[1] = {key,   A_bf + (size_t)NQ * CD,     NQ * CD / 4};
    ca.s[2] = {value, A_bf + (size_t)2 * NQ * CD, NQ * CD / 4};
    ca.s[3] = {ipw,   w_bf,                       3 * CD * CD / 4};
    ca.s[4] = {out_w, ow_bf,                      CD * CD / 4};
    dim3 g0(NQ * CD / 4 / 256, 5);
    convert_bf16<<<g0, 256, 0, stream>>>(ca);

    // 1) q/k/v projections (all bf16 out; q pre-scaled by 0.125)
    dim3 g1(NQ / 128, CD / 128, 3);
    qkv_gemm<<<g1, 256, 0, stream>>>(A_bf, w_bf, ipb, q_bf, k_bf, v_bf);

    // 2) gather attention -> bf16 attn + output 2
    attn_kernel<<<NQ, 512, 0, stream>>>(q_bf, k_bf, v_bf, index_pair,
                                        key_batch_cnt, index_pair_batch,
                                        attn_bf, out + (size_t)NQ * CD);

    // 3) out projection -> output 1
    dim3 g3(NQ / 128, CD / 128, 1);
    out_gemm<<<g3, 256, 0, stream>>>(attn_bf, ow_bf, out_b, out);
}

// Round 9
// 220.870 us; speedup vs baseline: 1.0558x; 1.0128x over previous
//
#include <hip/hip_runtime.h>
#include <hip/hip_bf16.h>
#include <math.h>

#define NQ 8192   // queries
#define MK 8192   // keys
#define CD 512    // embed dim
#define LN 64     // neighbors per query
#define HH 8      // heads
#define HD 64     // head dim
#define BB 16     // batches

typedef short short8 __attribute__((ext_vector_type(8)));
typedef float floatx4 __attribute__((ext_vector_type(4)));

// fp32 -> bf16 RNE scalar
__device__ __forceinline__ unsigned short f2bf(float x) {
    unsigned int u = __builtin_bit_cast(unsigned int, x);
    return (unsigned short)((u + 0x7FFFu + ((u >> 16) & 1u)) >> 16);
}
// packed pair via HW v_cvt_pk_bf16_f32 on gfx950
__device__ __forceinline__ unsigned int pkbf(float lo, float hi) {
    float2 f; f.x = lo; f.y = hi;
    __hip_bfloat162 h2 = __float22bfloat162_rn(f);
    unsigned int u;
    __builtin_memcpy(&u, &h2, 4);
    return u;
}
// bf16 pair low element -> float (exact)
__device__ __forceinline__ float bflo(unsigned int u) {
    return __builtin_bit_cast(float, u << 16);
}
// bf16 pair high element -> float WITH low-half junk bits: hi*(1+d),
// |d| <= 2^-8 — below bf16's own rounding noise; saves the mask op.
__device__ __forceinline__ float bfhij(unsigned int u) {
    return __builtin_bit_cast(float, u);
}
__device__ __forceinline__ short8 u4s8(uint4 u) {
    short8 s; __builtin_memcpy(&s, &u, 16); return s;
}

// async global->LDS, 16B per lane; LDS dest = wave-uniform base + lane*16
__device__ __forceinline__ void gl_lds16(const unsigned short* g, unsigned short* l) {
    __builtin_amdgcn_global_load_lds(
        (const __attribute__((address_space(1))) unsigned int*)g,
        (__attribute__((address_space(3))) unsigned int*)l, 16, 0, 0);
}

// ---------------------------------------------------------------------------
// fp32 -> bf16 conversion prepass (5 segments in one launch)
// ---------------------------------------------------------------------------
struct ConvSeg { const float* src; unsigned short* dst; int n4; };
struct ConvArgs { ConvSeg s[5]; };

__global__ __launch_bounds__(256) void convert_bf16(ConvArgs a) {
    const int seg = blockIdx.y;
    const int i = blockIdx.x * 256 + threadIdx.x;
    if (i >= a.s[seg].n4) return;
    const float4 v = ((const float4*)a.s[seg].src)[i];
    uint2 o; o.x = pkbf(v.x, v.y); o.y = pkbf(v.z, v.w);
    ((uint2*)a.s[seg].dst)[i] = o;
}

// ---------------------------------------------------------------------------
// m97-style bf16 NT GEMM, 64x128 tile (M halved vs R6 for 2x grid
// parallelism: qkv 1536 blocks = 6/CU, out 512 = 2/CU; the barrier-drain
// K-loop now overlaps across co-resident blocks). BK=64, 256 threads =
// 4 waves; all waves share the A rows, wave w owns cols [w*32, w*32+32).
// Staging via global_load_lds_dwordx4 with XOR-swizzled source granule
// (LDS[row][p] = A[row][p ^ (row&7)]) -> conflict-free ds_read_b128.
// ---------------------------------------------------------------------------
__device__ __forceinline__ void gemm_bf_body(const unsigned short* __restrict__ A,
                                             const unsigned short* __restrict__ W,
                                             const float* __restrict__ bias,
                                             float* __restrict__ outf,
                                             unsigned short* __restrict__ outb,
                                             float scale) {
    __shared__ unsigned short As[64 * 64];     // 8 KB
    __shared__ unsigned short Bs[128 * 64];    // 16 KB

    const int tid  = threadIdx.x;
    const int row0 = blockIdx.x * 64;
    const int col0 = blockIdx.y * 128;

    const int w    = tid >> 6;
    const int lane = tid & 63;
    const int q    = lane >> 4;    // quad
    const int ml   = lane & 15;

    const int sr = lane >> 3;            // 0..7 (== row&7 of the loaded row)
    const int sg = (lane & 7) ^ sr;      // XOR-swizzled source granule
    // wave w stages A rows [w*16, w*16+16) (2 instrs), B rows [w*32,+32) (4)
    const unsigned short* Ap = A + (size_t)(row0 + w * 16 + sr) * CD + sg * 8;
    const unsigned short* Wp = W + (size_t)(col0 + w * 32 + sr) * CD + sg * 8;
    unsigned short* Asw = &As[(w * 16) * 64];
    unsigned short* Bsw = &Bs[(w * 32) * 64];

    floatx4 acc[4][2];
#pragma unroll
    for (int i = 0; i < 4; ++i)
#pragma unroll
        for (int j = 0; j < 2; ++j)
            acc[i][j] = (floatx4){0.f, 0.f, 0.f, 0.f};

    for (int k0 = 0; k0 < CD; k0 += 64) {
        __syncthreads();
#pragma unroll
        for (int i = 0; i < 2; ++i)
            gl_lds16(Ap + (size_t)(i * 8) * CD + k0, Asw + i * 8 * 64);
#pragma unroll
        for (int i = 0; i < 4; ++i)
            gl_lds16(Wp + (size_t)(i * 8) * CD + k0, Bsw + i * 8 * 64);
        __syncthreads();

#pragma unroll
        for (int kw = 0; kw < 2; ++kw) {
            short8 af[4], bf[2];
            const int gp = ((kw * 4 + q) ^ (ml & 7)) * 8;
#pragma unroll
            for (int mi = 0; mi < 4; ++mi)
                af[mi] = *(const short8*)&As[(mi * 16 + ml) * 64 + gp];
#pragma unroll
            for (int ni = 0; ni < 2; ++ni)
                bf[ni] = *(const short8*)&Bs[(w * 32 + ni * 16 + ml) * 64 + gp];
#pragma unroll
            for (int mi = 0; mi < 4; ++mi)
#pragma unroll
                for (int ni = 0; ni < 2; ++ni)
                    acc[mi][ni] = __builtin_amdgcn_mfma_f32_16x16x32_bf16(
                        af[mi], bf[ni], acc[mi][ni], 0, 0, 0);
        }
    }

    float bv[2];
#pragma unroll
    for (int ni = 0; ni < 2; ++ni)
        bv[ni] = bias[col0 + w * 32 + ni * 16 + ml];
#pragma unroll
    for (int mi = 0; mi < 4; ++mi) {
#pragma unroll
        for (int ni = 0; ni < 2; ++ni) {
            const int cg = col0 + w * 32 + ni * 16 + ml;
#pragma unroll
            for (int rr = 0; rr < 4; ++rr) {
                const int rg = row0 + mi * 16 + q * 4 + rr;
                const float val = (acc[mi][ni][rr] + bv[ni]) * scale;
                if (outb) outb[(size_t)rg * CD + cg] = f2bf(val);
                else      outf[(size_t)rg * CD + cg] = val;
            }
        }
    }
}

// qkv: z=0 -> q bf16 (scale 0.125 folded pre-round); z=1 -> k bf16; z=2 -> v bf16
__global__ __launch_bounds__(256) void qkv_gemm(const unsigned short* __restrict__ A_bf,
                                                const unsigned short* __restrict__ w_bf,
                                                const float* __restrict__ bias,
                                                unsigned short* __restrict__ q_bf,
                                                unsigned short* __restrict__ k_bf,
                                                unsigned short* __restrict__ v_bf) {
    const int z = blockIdx.z;
    const unsigned short* A = A_bf + (size_t)z * NQ * CD;
    unsigned short* outb = (z == 0) ? q_bf : ((z == 1) ? k_bf : v_bf);
    gemm_bf_body(A, w_bf + (size_t)z * CD * CD, bias + (size_t)z * CD,
                 nullptr, outb, (z == 0) ? 0.125f : 1.0f);
}

__global__ __launch_bounds__(256) void out_gemm(const unsigned short* __restrict__ A,
                                                const unsigned short* __restrict__ W,
                                                const float* __restrict__ bias,
                                                float* __restrict__ out) {
    gemm_bf_body(A, W, bias, out, nullptr, 1.0f);
}

// ---------------------------------------------------------------------------
// Attention (R9): ONE WAVE = ONE QUERY, zero barriers. 256-thread blocks,
// 4 waves, wave w owns query (bx&7)*1024 + (bx>>3)*4 + w (XCD swizzle).
// Per wave: prefix-scan of key_batch_cnt (shfl), gather index per lane
// (lane=neighbor, validity = per-wave ballot mask), k/v row ids for the
// MFMA/PV lane layouts derived via __shfl (no LDS tables). Loop over 8
// heads: scores via 2 chained 16x16x32 MFMAs (A = gathered k rows,
// B = q broadcast; layouts proven by the GEMM above), publish through a
// wave-PRIVATE LDS strip (same-wave RAW, no barrier), softmax on shfl
// butterfly, PV on VALU fma, out2 accumulated in-register across heads.
// ---------------------------------------------------------------------------
__global__ __launch_bounds__(256) void attn_kernel(
    const unsigned short* __restrict__ q_bf,     // NQ*CD bf16 (pre-scaled)
    const unsigned short* __restrict__ k_bf,     // NQ*CD bf16
    const unsigned short* __restrict__ v_bf,     // NQ*CD bf16
    const int* __restrict__ index_pair,          // (NQ, LN)
    const int* __restrict__ key_batch_cnt,       // (BB,)
    const int* __restrict__ index_pair_batch,    // (NQ,)
    unsigned short* __restrict__ attn_bf,        // NQ*CD bf16
    float* __restrict__ out2) {                  // NQ*LN
    const int tid  = threadIdx.x;
    const int wid  = tid >> 6;
    const int lane = tid & 63;
    const int bx   = blockIdx.x;
    const int n    = (bx & 7) * (NQ / 8) + (bx >> 3) * 4 + wid;

    const int quad = lane >> 4;    // 0..3
    const int ml   = lane & 15;
    const int r    = lane >> 3;    // 0..7
    const int dg   = lane & 7;     // 0..7

    __shared__ float sc_s[4][LN];
    float* sc = sc_s[wid];         // wave-private score strip

    // key offset via parallel prefix scan (lanes 0..15)
    int cnt = (lane < BB) ? key_batch_cnt[lane] : 0;
#pragma unroll
    for (int d = 1; d < BB; d <<= 1) {
        const int t = __shfl_up(cnt, d, 64);
        if (lane >= d) cnt += t;
    }
    const int batch = index_pair_batch[n];
    const int off0  = (batch > 0) ? __shfl(cnt, batch - 1, 64) : 0;

    // gather indices: lane = neighbor
    const int gi = index_pair[n * LN + lane];
    const unsigned long long vmask = __ballot(gi >= 0);
    const int g = (gi >= 0) ? (gi + off0) : 0;   // reference safe-gather

    // rows for the MFMA A-frag (k) and PV (v) lane layouts, via bpermute
    int krow[4];
#pragma unroll
    for (int grp = 0; grp < 4; ++grp)
        krow[grp] = __shfl(g, grp * 16 + ml, 64);
    int vrow[8];
#pragma unroll
    for (int it = 0; it < 8; ++it)
        vrow[it] = __shfl(g, it * 8 + r, 64);

    const size_t qbase = (size_t)n * CD;
    float s8 = 0.f;                // out2 accumulator (lane = neighbor)

    for (int h = 0; h < HH; ++h) {
        // ---- loads (all independent; no barriers anywhere) --------------
        const char* qp = (const char*)(q_bf + qbase + h * HD) + quad * 16;
        const uint4 bq0 = *(const uint4*)qp;
        const uint4 bq1 = *(const uint4*)(qp + 64);
        uint4 a0[4], a1[4];
#pragma unroll
        for (int grp = 0; grp < 4; ++grp) {
            const char* kp = (const char*)(k_bf + (size_t)krow[grp] * CD + h * HD) + quad * 16;
            a0[grp] = *(const uint4*)kp;
            a1[grp] = *(const uint4*)(kp + 64);
        }
        uint4 vv[8];
#pragma unroll
        for (int it = 0; it < 8; ++it) {
            const char* vp = (const char*)(v_bf + (size_t)vrow[it] * CD + h * HD) + dg * 16;
            vv[it] = *(const uint4*)vp;
        }

        // ---- scores via MFMA (D col=lane&15, row=quad*4+reg) -------------
#pragma unroll
        for (int grp = 0; grp < 4; ++grp) {
            floatx4 sa = (floatx4){0.f, 0.f, 0.f, 0.f};
            sa = __builtin_amdgcn_mfma_f32_16x16x32_bf16(u4s8(a0[grp]), u4s8(bq0), sa, 0, 0, 0);
            sa = __builtin_amdgcn_mfma_f32_16x16x32_bf16(u4s8(a1[grp]), u4s8(bq1), sa, 0, 0, 0);
            if (ml == 0) {   // lanes 0,16,32,48 publish neighbors grp*16+quad*4+rr
#pragma unroll
                for (int rr = 0; rr < 4; ++rr) sc[grp * 16 + quad * 4 + rr] = sa[rr];
            }
        }

        // ---- softmax over 64 lanes (lane = neighbor; same-wave LDS RAW) --
        float score = sc[lane];
        if (!((vmask >> lane) & 1ull)) score = -1000.0f;   // MASK_VAL
        float mx = score;
#pragma unroll
        for (int o = 32; o > 0; o >>= 1) mx = fmaxf(mx, __shfl_xor(mx, o, 64));
        float e = __expf(score - mx);           // masked lanes underflow to 0
        float s = e;
#pragma unroll
        for (int o = 32; o > 0; o >>= 1) s += __shfl_xor(s, o, 64);
        const float w = e / s;
        s8 += w;

        // ---- PV: lane (r,dg); butterfly over r bits ----------------------
        float a8[8] = {0.f, 0.f, 0.f, 0.f, 0.f, 0.f, 0.f, 0.f};
#pragma unroll
        for (int it = 0; it < 8; ++it) {
            const float wl = __shfl(w, it * 8 + r, 64);
            a8[0] = fmaf(wl, bflo(vv[it].x),  a8[0]);
            a8[1] = fmaf(wl, bfhij(vv[it].x), a8[1]);
            a8[2] = fmaf(wl, bflo(vv[it].y),  a8[2]);
            a8[3] = fmaf(wl, bfhij(vv[it].y), a8[3]);
            a8[4] = fmaf(wl, bflo(vv[it].z),  a8[4]);
            a8[5] = fmaf(wl, bfhij(vv[it].z), a8[5]);
            a8[6] = fmaf(wl, bflo(vv[it].w),  a8[6]);
            a8[7] = fmaf(wl, bfhij(vv[it].w), a8[7]);
        }
#pragma unroll
        for (int o = 8; o <= 32; o <<= 1)
#pragma unroll
            for (int d = 0; d < 8; ++d) a8[d] += __shfl_xor(a8[d], o, 64);
        // lane (r,dg) stores dim dg*8+r
        attn_bf[qbase + h * HD + dg * 8 + r] = f2bf(a8[r]);
    }

    // ---- output 2: sum over heads / H (all in-register) ------------------
    out2[(size_t)n * LN + lane] = s8 * (1.0f / HH);
}

// ---------------------------------------------------------------------------
extern "C" void kernel_launch(void* const* d_in, const int* in_sizes, int n_in,
                              void* d_out, int out_size, void* d_ws, size_t ws_size,
                              hipStream_t stream) {
    const float* query   = (const float*)d_in[0];
    const float* key     = (const float*)d_in[1];
    const float* value   = (const float*)d_in[2];
    const float* ipw     = (const float*)d_in[3];   // (3C, C)
    const float* ipb     = (const float*)d_in[4];   // (3C,)
    const float* out_w   = (const float*)d_in[5];   // (C, C)
    const float* out_b   = (const float*)d_in[6];   // (C,)
    const int*   index_pair       = (const int*)d_in[7];
    // d_in[8] = query_batch_cnt (unused: implied by index_pair_batch)
    const int*   key_batch_cnt    = (const int*)d_in[9];
    const int*   index_pair_batch = (const int*)d_in[10];

    float* out = (float*)d_out;                // [attn (NQ*CD) | out2 (NQ*LN)]
    // ws layout (bf16): q 8MB | k 8 | v 8 | A_in 24 | ipw 3 | out_w 1
    unsigned short* q_bf  = (unsigned short*)d_ws;
    unsigned short* k_bf  = q_bf + (size_t)NQ * CD;
    unsigned short* v_bf  = k_bf + (size_t)NQ * CD;
    unsigned short* A_bf  = v_bf + (size_t)NQ * CD;        // 3 * NQ*CD
    unsigned short* w_bf  = A_bf + (size_t)3 * NQ * CD;    // 3 * CD*CD (ipw)
    unsigned short* ow_bf = w_bf + (size_t)3 * CD * CD;    // CD*CD (out_w)
    // attn output (bf16) reuses the A_bf query slot (qkv_gemm done with it)
    unsigned short* attn_bf = A_bf;

    // 0) convert inputs/weights to bf16
    ConvArgs ca;
    ca.s[0] = {query, A_bf,                       NQ * CD / 4};
    ca.s[1] = {key,   A_bf + (size_t)NQ * CD,     NQ * CD / 4};
    ca.s[2] = {value, A_bf + (size_t)2 * NQ * CD, NQ * CD / 4};
    ca.s[3] = {ipw,   w_bf,                       3 * CD * CD / 4};
    ca.s[4] = {out_w, ow_bf,                      CD * CD / 4};
    dim3 g0(NQ * CD / 4 / 256, 5);
    convert_bf16<<<g0, 256, 0, stream>>>(ca);

    // 1) q/k/v projections (all bf16 out; q pre-scaled by 0.125)
    dim3 g1(NQ / 64, CD / 128, 3);
    qkv_gemm<<<g1, 256, 0, stream>>>(A_bf, w_bf, ipb, q_bf, k_bf, v_bf);

    // 2) gather attention -> bf16 attn + output 2
    attn_kernel<<<NQ / 4, 256, 0, stream>>>(q_bf, k_bf, v_bf, index_pair,
                                            key_batch_cnt, index_pair_batch,
                                            attn_bf, out + (size_t)NQ * CD);

    // 3) out projection -> output 1
    dim3 g3(NQ / 64, CD / 128, 1);
    out_gemm<<<g3, 256, 0, stream>>>(attn_bf, ow_bf, out_b, out);
}